// Round 3
// baseline (115.485 us; speedup 1.0000x reference)
//
#include <hip/hip_runtime.h>
#include <hip/hip_bf16.h>
#include <cstdint>
#include <cstddef>
#include <math.h>

#define D 256
#define TEMP_INV 2.0f       // 1 / TEMPERATURE, TEMPERATURE = 0.5
#define EPS_NORM 1e-8f
#define NTILES 2080         // 64*65/2 upper-triangular 128x128 tiles

typedef __attribute__((ext_vector_type(8))) short bf16x8;
typedef __attribute__((ext_vector_type(4))) float f32x4;

// async 16B global->LDS. LDS dest must be wave-uniform; HW adds lane*16.
#define GLOAD16(g, l)                                                   \
  __builtin_amdgcn_global_load_lds(                                     \
      (const __attribute__((address_space(1))) void*)(g),               \
      (__attribute__((address_space(3))) void*)(l), 16, 0, 0)

// ---------------- kernel 1: normalize rows, write bf16 zn ----------------
// 512 blocks x 4 waves, grid-stride over 8192 rows (4 rows/wave).
__global__ void __launch_bounds__(256) normalize_rows(
    const float* __restrict__ zi, const float* __restrict__ zj,
    __hip_bfloat16* __restrict__ zn, float* __restrict__ out, int B) {
  const int wid = threadIdx.x >> 6;
  const int lane = threadIdx.x & 63;
  if (blockIdx.x == 0 && threadIdx.x == 0) out[0] = 0.0f;  // for finalize atomic
#pragma unroll
  for (int it = 0; it < 4; ++it) {
    int row = it * 2048 + blockIdx.x * 4 + wid;
    const float* src = (row < B) ? (zi + (size_t)row * D)
                                 : (zj + (size_t)(row - B) * D);
    float4 v = ((const float4*)src)[lane];
    float ss = v.x * v.x + v.y * v.y + v.z * v.z + v.w * v.w;
    for (int off = 32; off; off >>= 1) ss += __shfl_xor(ss, off);
    float rn = 1.0f / fmaxf(sqrtf(ss), EPS_NORM);
    union { ushort4 u; __hip_bfloat16 h[4]; } o;
    o.h[0] = __float2bfloat16(v.x * rn);
    o.h[1] = __float2bfloat16(v.y * rn);
    o.h[2] = __float2bfloat16(v.z * rn);
    o.h[3] = __float2bfloat16(v.w * rn);
    ((ushort4*)zn)[(size_t)row * (D / 4) + lane] = o.u;
  }
}

// ---------------- kernel 2: fused sim GEMM + exp + masked row/col sums ---
// Upper-triangular 128x128 tiles, 2080 blocks, BK=64, K=256 (4 steps).
//
// R10 (this round): async staging + double buffer => ONE barrier/K-step.
//  - global_load_lds (16B) replaces the reg round-trip (no float4s live
//    across barriers, frees VGPRs, no ds_write instructions at all).
//  - LDS image must stay linear for global_load_lds (m104), so the XOR
//    bank swizzle moves to the GLOBAL source column: lane fetches chunk
//    c8^lr, landing at linear chunk c8 => LDS[r][c] = global[r][c^(r&7)],
//    bit-identical to the R9 layout; read-side addressing unchanged.
//  - Double-buffered LDS (2 x (16+16) KB = 64 KB, 2 blocks/CU): loads for
//    step t+1 issue before step t's MFMA phase; the single __syncthreads
//    per step provides exactly the vmcnt(0)+barrier the buffer flip needs.
//    (R9 had 2 full-drain barriers per step + WAR serialization.)
// Floors: MFMA 7 us (17.4 GFLOP), L2 panel traffic 266 MB ~ 7.7 us.
__device__ __forceinline__ void decode_tile(int t, int Nb, int& by, int& bx) {
  float fb = (2.0f * Nb + 1.0f -
              sqrtf((float)((2 * Nb + 1) * (2 * Nb + 1) - 8 * t))) * 0.5f;
  int y = (int)fb;
  while ((y + 1) * Nb - ((y + 1) * y) / 2 <= t) ++y;
  while (y * Nb - (y * (y - 1)) / 2 > t) --y;
  by = y;
  bx = y + (t - (y * Nb - (y * (y - 1)) / 2));
}

__global__ void __launch_bounds__(256, 2) ntxent_gemm(
    const __hip_bfloat16* __restrict__ zn,
    float* __restrict__ part, float* __restrict__ pos, int B) {
  __shared__ __align__(16) __hip_bfloat16 Ash[2][128 * 64];  // 2 x 16 KB
  __shared__ __align__(16) __hip_bfloat16 Bsh[2][128 * 64];  // 2 x 16 KB

  const int N = 2 * B;
  const int Nb = N / 128;  // 64
  int by, bx;
  decode_tile(blockIdx.x, Nb, by, bx);
  const int bm = by * 128;
  const int bn = bx * 128;
  const bool isDiag = (by == bx);
  const bool isPos = (bx == by + B / 128);

  const int tid = threadIdx.x;
  const int wid = tid >> 6;
  const int lane = tid & 63;
  const int wy = wid >> 1, wx = wid & 1;
  const int wrow0 = wid * 32;

  const int lr = lane >> 3;     // row within 8-row staging group (== r&7)
  const int c8 = lane & 7;      // linear 16B chunk this lane lands in (LDS)

  const int frow = lane & 15;
  const int quad = lane >> 4;
  const int f7 = frow & 7;

  f32x4 acc[4][4] = {};

  // pre-swizzled global source: fetch chunk c8^lr so the linear LDS write
  // (dest chunk c8) realizes LDS[r][c] = global[r][c ^ (r&7)].
  const __hip_bfloat16* gA =
      zn + (size_t)(bm + wrow0 + lr) * D + (c8 ^ lr) * 8;
  const __hip_bfloat16* gB =
      zn + (size_t)(bn + wrow0 + lr) * D + (c8 ^ lr) * 8;

  // prologue: stage k0=0 into buffer 0 (4 x 8-row slabs per wave, A and B)
#pragma unroll
  for (int s = 0; s < 4; ++s) {
    GLOAD16(gA + s * 8 * D, &Ash[0][(wrow0 + s * 8) * 64]);
    GLOAD16(gB + s * 8 * D, &Bsh[0][(wrow0 + s * 8) * 64]);
  }
  __syncthreads();  // vmcnt(0) drain + barrier: buffer 0 ready

#pragma unroll
  for (int k0i = 0; k0i < 4; ++k0i) {
    const int cur = k0i & 1;
    // issue next slab's loads first: they fly under the MFMA phase and are
    // drained by this step's closing __syncthreads (vmcnt(0)).
    if (k0i < 3) {
      const int k0 = (k0i + 1) * 64;
#pragma unroll
      for (int s = 0; s < 4; ++s) {
        GLOAD16(gA + s * 8 * D + k0, &Ash[cur ^ 1][(wrow0 + s * 8) * 64]);
        GLOAD16(gB + s * 8 * D + k0, &Bsh[cur ^ 1][(wrow0 + s * 8) * 64]);
      }
    }
#pragma unroll
    for (int kk = 0; kk < 2; ++kk) {
      bf16x8 a[4], b[4];
#pragma unroll
      for (int i = 0; i < 4; ++i)
        a[i] = *(const bf16x8*)
            &Ash[cur][(wy * 64 + i * 16 + frow) * 64 + ((kk * 4 + quad) ^ f7) * 8];
#pragma unroll
      for (int j = 0; j < 4; ++j)
        b[j] = *(const bf16x8*)
            &Bsh[cur][(wx * 64 + j * 16 + frow) * 64 + ((kk * 4 + quad) ^ f7) * 8];
#pragma unroll
      for (int i = 0; i < 4; ++i)
#pragma unroll
        for (int j = 0; j < 4; ++j)
          acc[i][j] =
              __builtin_amdgcn_mfma_f32_16x16x32_bf16(a[i], b[j], acc[i][j], 0, 0, 0);
    }
    __syncthreads();  // lgkm drained (this buf's reads done) + next buf ready
  }

  // ---- epilogue: exp + masked row/col sums -> LDS combine -> part writes
  float* red = (float*)&Ash[0][0];  // red[0..255]: rowbuf[128][2] (x wx)
                                    // red[256..511]: colbuf[128][2] (x wy)

  // C/D layout: col = lane&15, row = quad*4 + reg
  const int colq = lane & 15;
  float cs[4] = {0.0f, 0.0f, 0.0f, 0.0f};
#pragma unroll
  for (int i = 0; i < 4; ++i) {
#pragma unroll
    for (int r = 0; r < 4; ++r) {
      int rowloc = wy * 64 + i * 16 + quad * 4 + r;
      int row = bm + rowloc;
      float rs = 0.0f;
#pragma unroll
      for (int j = 0; j < 4; ++j) {
        int col = bn + wx * 64 + j * 16 + colq;
        float v = acc[i][j][r];
        float e = __expf(v * TEMP_INV);
        e = (isDiag && col == row) ? 0.0f : e;
        rs += e;
        cs[j] += e;
        if (isPos && col == row + B) { pos[row] = v; pos[col] = v; }
      }
      rs += __shfl_xor(rs, 1);
      rs += __shfl_xor(rs, 2);
      rs += __shfl_xor(rs, 4);
      rs += __shfl_xor(rs, 8);
      if (colq == 0) red[rowloc * 2 + wx] = rs;
    }
  }
#pragma unroll
  for (int j = 0; j < 4; ++j) {
    float c = cs[j];
    c += __shfl_xor(c, 16);
    c += __shfl_xor(c, 32);
    if (quad == 0) red[256 + (wx * 64 + j * 16 + colq) * 2 + wy] = c;
  }
  __syncthreads();
  // part slot layout: for global row idx in row-tile ty, slot s holds the
  // contribution of column-tile s (row-sum from block (ty,s), s>=ty) or
  // row-tile s (col-sum from block (s,ty), s<ty). Each slot written once.
  if (tid < 128) {
    part[(size_t)bx * N + bm + tid] = red[tid * 2] + red[tid * 2 + 1];
  } else if (!isDiag) {
    int t = tid - 128;
    part[(size_t)by * N + bn + t] = red[256 + t * 2] + red[256 + t * 2 + 1];
  }
}

// ---------------- kernel 3: reduce partials + finalize loss scalar -------
// 32 blocks x 256 threads; thread owns one global row idx.
__global__ void __launch_bounds__(256) finalize(
    const float* __restrict__ part, const float* __restrict__ pos,
    float* __restrict__ out, int N) {
  const int idx = blockIdx.x * 256 + threadIdx.x;
  const int NS = N / 128;  // 64 slots
  float s = 0.0f;
#pragma unroll 8
  for (int k = 0; k < NS; ++k) s += part[(size_t)k * N + idx];
  float loss = __logf(s) - pos[idx] * TEMP_INV;
  for (int off = 32; off; off >>= 1) loss += __shfl_xor(loss, off);
  __shared__ float redsh[4];
  if ((threadIdx.x & 63) == 0) redsh[threadIdx.x >> 6] = loss;
  __syncthreads();
  if (threadIdx.x == 0) {
    float t = redsh[0] + redsh[1] + redsh[2] + redsh[3];
    atomicAdd(out, t / (float)N);
  }
}

extern "C" void kernel_launch(void* const* d_in, const int* in_sizes, int n_in,
                              void* d_out, int out_size, void* d_ws, size_t ws_size,
                              hipStream_t stream) {
  const float* zi = (const float*)d_in[0];
  const float* zj = (const float*)d_in[1];
  const int B = in_sizes[0] / D;  // 4096
  const int N = 2 * B;            // 8192

  __hip_bfloat16* zn = (__hip_bfloat16*)d_ws;
  float* pos = (float*)((char*)d_ws + (size_t)N * D * sizeof(__hip_bfloat16));
  float* part = pos + N;          // [N/128][N] floats = 2 MB

  normalize_rows<<<512, 256, 0, stream>>>(zi, zj, zn, (float*)d_out, B);
  ntxent_gemm<<<NTILES, 256, 0, stream>>>(zn, part, pos, B);
  finalize<<<N / 256, 256, 0, stream>>>(part, pos, (float*)d_out, N);
}

// Round 4
// 115.335 us; speedup vs baseline: 1.0013x; 1.0013x over previous
//
#include <hip/hip_runtime.h>
#include <hip/hip_bf16.h>
#include <cstdint>
#include <cstddef>
#include <math.h>

#define D 256
#define TEMP_INV 2.0f       // 1 / TEMPERATURE, TEMPERATURE = 0.5
#define EPS_NORM 1e-8f
#define NTILES 2080         // 64*65/2 upper-triangular 128x128 tiles

typedef __attribute__((ext_vector_type(8))) short bf16x8;
typedef __attribute__((ext_vector_type(4))) float f32x4;

// async 16B global->LDS. LDS dest must be wave-uniform; HW adds lane*16.
#define GLOAD16(g, l)                                                   \
  __builtin_amdgcn_global_load_lds(                                     \
      (const __attribute__((address_space(1))) void*)(g),               \
      (__attribute__((address_space(3))) void*)(l), 16, 0, 0)

// ---------------- kernel 1: normalize rows, write bf16 zn ----------------
// 512 blocks x 4 waves, grid-stride over 8192 rows (4 rows/wave).
__global__ void __launch_bounds__(256) normalize_rows(
    const float* __restrict__ zi, const float* __restrict__ zj,
    __hip_bfloat16* __restrict__ zn, float* __restrict__ out, int B) {
  const int wid = threadIdx.x >> 6;
  const int lane = threadIdx.x & 63;
  if (blockIdx.x == 0 && threadIdx.x == 0) out[0] = 0.0f;  // for finalize atomic
#pragma unroll
  for (int it = 0; it < 4; ++it) {
    int row = it * 2048 + blockIdx.x * 4 + wid;
    const float* src = (row < B) ? (zi + (size_t)row * D)
                                 : (zj + (size_t)(row - B) * D);
    float4 v = ((const float4*)src)[lane];
    float ss = v.x * v.x + v.y * v.y + v.z * v.z + v.w * v.w;
    for (int off = 32; off; off >>= 1) ss += __shfl_xor(ss, off);
    float rn = 1.0f / fmaxf(sqrtf(ss), EPS_NORM);
    union { ushort4 u; __hip_bfloat16 h[4]; } o;
    o.h[0] = __float2bfloat16(v.x * rn);
    o.h[1] = __float2bfloat16(v.y * rn);
    o.h[2] = __float2bfloat16(v.z * rn);
    o.h[3] = __float2bfloat16(v.w * rn);
    ((ushort4*)zn)[(size_t)row * (D / 4) + lane] = o.u;
  }
}

// ---------------- kernel 2: fused sim GEMM + exp + masked row/col sums ---
// Upper-triangular 128x128 tiles, 2080 blocks. R11: NO K-LOOP.
//
// R10 post-mortem: dbuf+gload_lds regressed (54 us, occupancy 17%) — the
// vmcnt(0)-draining barrier per thin K-step with only 2 blocks/CU is the
// structural stall (matches m97-ceiling history). K=256 is small enough to
// drop the K-loop entirely:
//  - A in REGISTERS: wave w owns M rows [w*32,w*32+32) x all 128 cols.
//    The mfma A-frag layout == plain coalesced global loads (row m*16+frow,
//    16B at kc*64+quad*16): 16 loads/wave, no LDS, no ds_reads for A.
//    aF[2][8] = 64 VGPR; acc[2][8] = 64 AGPR; fits (256,2) cap.
//  - B SINGLE-SHOT in LDS, 4 slabs of [128][64] so the verified R9/R10
//    swizzle geometry is reused bit-identically: gload_lds with
//    pre-swizzled SOURCE column (c8^lr), linear dest; reads at
//    ((kk*4+quad)^f7) — measured 0 bank conflicts.
//  - Hot loop has ZERO barriers: stage(32+16 loads) -> one __syncthreads
//    -> 64 ds_read_b128 + 128 MFMA straight through. 64 KB LDS ->
//    2 blocks/CU; one block's load phase hides under the other's MFMAs.
// Floors: MFMA ~2066 cy/block, L2 128KB ~2340 cy/block, 8.1 blocks/CU.
__device__ __forceinline__ void decode_tile(int t, int Nb, int& by, int& bx) {
  float fb = (2.0f * Nb + 1.0f -
              sqrtf((float)((2 * Nb + 1) * (2 * Nb + 1) - 8 * t))) * 0.5f;
  int y = (int)fb;
  while ((y + 1) * Nb - ((y + 1) * y) / 2 <= t) ++y;
  while (y * Nb - (y * (y - 1)) / 2 > t) --y;
  by = y;
  bx = y + (t - (y * Nb - (y * (y - 1)) / 2));
}

__global__ void __launch_bounds__(256, 2) ntxent_gemm(
    const __hip_bfloat16* __restrict__ zn,
    float* __restrict__ part, float* __restrict__ pos, int B) {
  __shared__ __align__(16) __hip_bfloat16 Bsh[4][128 * 64];  // 64 KB

  const int N = 2 * B;
  const int Nb = N / 128;  // 64
  int by, bx;
  decode_tile(blockIdx.x, Nb, by, bx);
  const int bm = by * 128;
  const int bn = bx * 128;
  const bool isDiag = (by == bx);
  const bool isPos = (bx == by + B / 128);

  const int tid = threadIdx.x;
  const int w = tid >> 6;       // wave id = M-slice owner
  const int lane = tid & 63;
  const int frow = lane & 15;   // == colq in epilogue
  const int quad = lane >> 4;
  const int f7 = frow & 7;
  const int lr = lane >> 3;     // staging row within 8-row group
  const int c8 = lane & 7;      // staging 16B chunk (linear LDS dest)

  // ---- stage B: wave w stages rows [w*32, w*32+32) of all 4 k-slabs.
  // source column pre-swizzled (c8^lr) so linear LDS image realizes
  // LDS[r][c] = global[r][c ^ (r&7)] within each 64-col slab.
  const __hip_bfloat16* gB =
      zn + (size_t)(bn + w * 32 + lr) * D + (c8 ^ lr) * 8;
#pragma unroll
  for (int kb = 0; kb < 4; ++kb)
#pragma unroll
    for (int s = 0; s < 4; ++s)
      GLOAD16(gB + (size_t)s * 8 * D + kb * 64,
              &Bsh[kb][(w * 32 + s * 8) * 64]);

  // ---- A straight to registers in MFMA fragment layout
  bf16x8 aF[2][8];
  const __hip_bfloat16* gA =
      zn + (size_t)(bm + w * 32 + frow) * D + quad * 8;
#pragma unroll
  for (int m = 0; m < 2; ++m)
#pragma unroll
    for (int kc = 0; kc < 8; ++kc)
      aF[m][kc] = *(const bf16x8*)(gA + (size_t)m * 16 * D + kc * 32);

  __syncthreads();  // vmcnt(0) drain + barrier: B resident, aF resident

  f32x4 acc[2][8] = {};
#pragma unroll
  for (int kc = 0; kc < 8; ++kc) {
    const int kb = kc >> 1, kk = kc & 1;
    bf16x8 b[8];
#pragma unroll
    for (int j = 0; j < 8; ++j)
      b[j] = *(const bf16x8*)
          &Bsh[kb][(j * 16 + frow) * 64 + ((kk * 4 + quad) ^ f7) * 8];
#pragma unroll
    for (int j = 0; j < 8; ++j) {
      acc[0][j] = __builtin_amdgcn_mfma_f32_16x16x32_bf16(aF[0][kc], b[j],
                                                          acc[0][j], 0, 0, 0);
      acc[1][j] = __builtin_amdgcn_mfma_f32_16x16x32_bf16(aF[1][kc], b[j],
                                                          acc[1][j], 0, 0, 0);
    }
  }

  // ---- epilogue. C/D layout: col = lane&15, row = quad*4 + reg.
  // Rows are wave-exclusive (wave w owns 32 rows) -> direct row-sum store.
  const int colq = frow;
  float cs[8] = {};
#pragma unroll
  for (int m = 0; m < 2; ++m) {
#pragma unroll
    for (int r = 0; r < 4; ++r) {
      int row = bm + w * 32 + m * 16 + quad * 4 + r;
      float rs = 0.0f;
#pragma unroll
      for (int j = 0; j < 8; ++j) {
        int col = bn + j * 16 + colq;
        float v = acc[m][j][r];
        float e = __expf(v * TEMP_INV);
        e = (isDiag && col == row) ? 0.0f : e;
        rs += e;
        cs[j] += e;
        if (isPos && col == row + B) { pos[row] = v; pos[col] = v; }
      }
      rs += __shfl_xor(rs, 1);
      rs += __shfl_xor(rs, 2);
      rs += __shfl_xor(rs, 4);
      rs += __shfl_xor(rs, 8);
      if (colq == 0) part[(size_t)bx * N + row] = rs;
    }
  }
  // col sums need cross-wave combine (each wave spans all 128 cols)
  float* colbuf = (float*)&Bsh[0][0];  // [128][4]
  __syncthreads();  // all waves done reading Bsh
#pragma unroll
  for (int j = 0; j < 8; ++j) {
    float c = cs[j];
    c += __shfl_xor(c, 16);
    c += __shfl_xor(c, 32);
    if (quad == 0) colbuf[(j * 16 + colq) * 4 + w] = c;
  }
  __syncthreads();
  // part slot layout: for row idx in row-tile ty, slot s holds contribution
  // of block (ty,s) row-sum (s>=ty) or block (s,ty) col-sum (s<ty).
  if (!isDiag && tid < 128) {
    part[(size_t)by * N + bn + tid] = colbuf[tid * 4 + 0] + colbuf[tid * 4 + 1] +
                                      colbuf[tid * 4 + 2] + colbuf[tid * 4 + 3];
  }
}

// ---------------- kernel 3: reduce partials + finalize loss scalar -------
// 32 blocks x 256 threads; thread owns one global row idx.
__global__ void __launch_bounds__(256) finalize(
    const float* __restrict__ part, const float* __restrict__ pos,
    float* __restrict__ out, int N) {
  const int idx = blockIdx.x * 256 + threadIdx.x;
  const int NS = N / 128;  // 64 slots
  float s = 0.0f;
#pragma unroll 8
  for (int k = 0; k < NS; ++k) s += part[(size_t)k * N + idx];
  float loss = __logf(s) - pos[idx] * TEMP_INV;
  for (int off = 32; off; off >>= 1) loss += __shfl_xor(loss, off);
  __shared__ float redsh[4];
  if ((threadIdx.x & 63) == 0) redsh[threadIdx.x >> 6] = loss;
  __syncthreads();
  if (threadIdx.x == 0) {
    float t = redsh[0] + redsh[1] + redsh[2] + redsh[3];
    atomicAdd(out, t / (float)N);
  }
}

extern "C" void kernel_launch(void* const* d_in, const int* in_sizes, int n_in,
                              void* d_out, int out_size, void* d_ws, size_t ws_size,
                              hipStream_t stream) {
  const float* zi = (const float*)d_in[0];
  const float* zj = (const float*)d_in[1];
  const int B = in_sizes[0] / D;  // 4096
  const int N = 2 * B;            // 8192

  __hip_bfloat16* zn = (__hip_bfloat16*)d_ws;
  float* pos = (float*)((char*)d_ws + (size_t)N * D * sizeof(__hip_bfloat16));
  float* part = pos + N;          // [N/128][N] floats = 2 MB

  normalize_rows<<<512, 256, 0, stream>>>(zi, zj, zn, (float*)d_out, B);
  ntxent_gemm<<<NTILES, 256, 0, stream>>>(zn, part, pos, B);
  finalize<<<N / 256, 256, 0, stream>>>(part, pos, (float*)d_out, N);
}

// Round 5
// 112.621 us; speedup vs baseline: 1.0254x; 1.0241x over previous
//
#include <hip/hip_runtime.h>
#include <hip/hip_bf16.h>
#include <cstdint>
#include <cstddef>
#include <math.h>

#define D 256
#define TEMP_INV 2.0f       // 1 / TEMPERATURE, TEMPERATURE = 0.5
#define EPS_NORM 1e-8f
#define NTILES 2080         // 64*65/2 upper-triangular 128x128 tiles

typedef __attribute__((ext_vector_type(8))) short bf16x8;
typedef __attribute__((ext_vector_type(4))) float f32x4;

// ---------------- kernel 1: normalize rows, write bf16 zn ----------------
// 512 blocks x 4 waves, grid-stride over 8192 rows (4 rows/wave).
__global__ void __launch_bounds__(256) normalize_rows(
    const float* __restrict__ zi, const float* __restrict__ zj,
    __hip_bfloat16* __restrict__ zn, float* __restrict__ out, int B) {
  const int wid = threadIdx.x >> 6;
  const int lane = threadIdx.x & 63;
  if (blockIdx.x == 0 && threadIdx.x == 0) out[0] = 0.0f;  // for finalize atomic
#pragma unroll
  for (int it = 0; it < 4; ++it) {
    int row = it * 2048 + blockIdx.x * 4 + wid;
    const float* src = (row < B) ? (zi + (size_t)row * D)
                                 : (zj + (size_t)(row - B) * D);
    float4 v = ((const float4*)src)[lane];
    float ss = v.x * v.x + v.y * v.y + v.z * v.z + v.w * v.w;
    for (int off = 32; off; off >>= 1) ss += __shfl_xor(ss, off);
    float rn = 1.0f / fmaxf(sqrtf(ss), EPS_NORM);
    union { ushort4 u; __hip_bfloat16 h[4]; } o;
    o.h[0] = __float2bfloat16(v.x * rn);
    o.h[1] = __float2bfloat16(v.y * rn);
    o.h[2] = __float2bfloat16(v.z * rn);
    o.h[3] = __float2bfloat16(v.w * rn);
    ((ushort4*)zn)[(size_t)row * (D / 4) + lane] = o.u;
  }
}

// ---------------- kernel 2: fused sim GEMM + exp + masked row/col sums ---
// Upper-triangular 128x128 tiles, 2080 blocks, NO K-loop (K=256 resident).
//
// R12: R11 skeleton + R9-verified staging path. R10/R11 post-mortem: both
// used swizzled-SOURCE global_load_lds; the source swizzle permutes 16B
// chunks within each 128B row segment, so the TA can't merge -> ~64 tiny
// requests per instruction, ~9k req/block: request-rate wall (the prior
// session hit the same wall in R4/R5, ~112 req/cyc). Removing all barriers
// (R11) changed nothing => stall is the request path, not sync.
// Fix: lane-SEQUENTIAL float4 global loads (contiguous 1024B/instr, TA
// merges fully) -> registers -> ds_write_b128 with the XOR swizzle on the
// LDS ADDRESS. Write & read patterns both measured 0-conflict in R4-R9.
// LDS image identical to R11: LDS[kb][r][c] = B[r][kb*8 + (c^(r&7))].
//  - A in REGISTERS (R11): wave w owns rows [w*32,w*32+32); mfma A-frags
//    load directly (row m*16+frow, 16B at kc*64+quad*16), 64B-merged.
//  - ONE barrier before compute; 64 ds_read + 128 MFMA straight through.
//  - Staging regs (16 float4) are fully unrolled (constant indices ->
//    registers) and dead before the barrier (no cross-barrier liveness).
__device__ __forceinline__ void decode_tile(int t, int Nb, int& by, int& bx) {
  float fb = (2.0f * Nb + 1.0f -
              sqrtf((float)((2 * Nb + 1) * (2 * Nb + 1) - 8 * t))) * 0.5f;
  int y = (int)fb;
  while ((y + 1) * Nb - ((y + 1) * y) / 2 <= t) ++y;
  while (y * Nb - (y * (y - 1)) / 2 > t) --y;
  by = y;
  bx = y + (t - (y * Nb - (y * (y - 1)) / 2));
}

__global__ void __launch_bounds__(256, 2) ntxent_gemm(
    const __hip_bfloat16* __restrict__ zn,
    float* __restrict__ part, float* __restrict__ pos, int B) {
  __shared__ __align__(16) __hip_bfloat16 Bsh[4][128 * 64];  // 64 KB

  const int N = 2 * B;
  const int Nb = N / 128;  // 64
  int by, bx;
  decode_tile(blockIdx.x, Nb, by, bx);
  const int bm = by * 128;
  const int bn = bx * 128;
  const bool isDiag = (by == bx);
  const bool isPos = (bx == by + B / 128);

  const int tid = threadIdx.x;
  const int w = tid >> 6;       // wave id = M-slice owner
  const int lane = tid & 63;
  const int frow = lane & 15;   // == colq in epilogue
  const int quad = lane >> 4;
  const int f7 = frow & 7;

  // ---- B staging geometry (lane-sequential in GLOBAL memory):
  // round r covers rows 8r..8r+7; thread tid handles row rr = 8r + (tid>>5),
  // global 16B-chunk g = tid&31 (contiguous across tid => merged requests).
  // LDS dest: slab kb = g>>3, swizzled chunk cp = (g&7) ^ (rr&7); rr&7 ==
  // tid>>5 for every round (rows step by 8), so cp is round-invariant.
  const int rr0 = tid >> 5;          // 0..7
  const int g5 = tid & 31;           // global chunk
  const int kb_w = g5 >> 3;          // dest slab
  const int cp = (tid & 7) ^ rr0;    // swizzled chunk within slab
  const __hip_bfloat16* gB0 = zn + (size_t)(bn + rr0) * D + g5 * 8;
  __hip_bfloat16* ldsW = &Bsh[kb_w][rr0 * 64 + cp * 8];

  // issue all B loads (lane-sequential, 16 x 1024B contiguous per wave)
  float4 v0 = *(const float4*)(gB0 + (size_t)(0 * 8) * D);
  float4 v1 = *(const float4*)(gB0 + (size_t)(1 * 8) * D);
  float4 v2 = *(const float4*)(gB0 + (size_t)(2 * 8) * D);
  float4 v3 = *(const float4*)(gB0 + (size_t)(3 * 8) * D);
  float4 v4 = *(const float4*)(gB0 + (size_t)(4 * 8) * D);
  float4 v5 = *(const float4*)(gB0 + (size_t)(5 * 8) * D);
  float4 v6 = *(const float4*)(gB0 + (size_t)(6 * 8) * D);
  float4 v7 = *(const float4*)(gB0 + (size_t)(7 * 8) * D);
  float4 v8 = *(const float4*)(gB0 + (size_t)(8 * 8) * D);
  float4 v9 = *(const float4*)(gB0 + (size_t)(9 * 8) * D);
  float4 va = *(const float4*)(gB0 + (size_t)(10 * 8) * D);
  float4 vb = *(const float4*)(gB0 + (size_t)(11 * 8) * D);
  float4 vc = *(const float4*)(gB0 + (size_t)(12 * 8) * D);
  float4 vd = *(const float4*)(gB0 + (size_t)(13 * 8) * D);
  float4 ve = *(const float4*)(gB0 + (size_t)(14 * 8) * D);
  float4 vf = *(const float4*)(gB0 + (size_t)(15 * 8) * D);

  // ---- A straight to registers in MFMA fragment layout (64B-merged rows)
  bf16x8 aF[2][8];
  const __hip_bfloat16* gA =
      zn + (size_t)(bm + w * 32 + frow) * D + quad * 8;
#pragma unroll
  for (int m = 0; m < 2; ++m)
#pragma unroll
    for (int kc = 0; kc < 8; ++kc)
      aF[m][kc] = *(const bf16x8*)(gA + (size_t)m * 16 * D + kc * 32);

  // ds_write B (swizzled LDS address; 0-conflict pattern per R4-R9)
  *(float4*)(ldsW + 0 * 8 * 64) = v0;
  *(float4*)(ldsW + 1 * 8 * 64) = v1;
  *(float4*)(ldsW + 2 * 8 * 64) = v2;
  *(float4*)(ldsW + 3 * 8 * 64) = v3;
  *(float4*)(ldsW + 4 * 8 * 64) = v4;
  *(float4*)(ldsW + 5 * 8 * 64) = v5;
  *(float4*)(ldsW + 6 * 8 * 64) = v6;
  *(float4*)(ldsW + 7 * 8 * 64) = v7;
  *(float4*)(ldsW + 8 * 8 * 64) = v8;
  *(float4*)(ldsW + 9 * 8 * 64) = v9;
  *(float4*)(ldsW + 10 * 8 * 64) = va;
  *(float4*)(ldsW + 11 * 8 * 64) = vb;
  *(float4*)(ldsW + 12 * 8 * 64) = vc;
  *(float4*)(ldsW + 13 * 8 * 64) = vd;
  *(float4*)(ldsW + 14 * 8 * 64) = ve;
  *(float4*)(ldsW + 15 * 8 * 64) = vf;

  __syncthreads();  // B resident in LDS, aF resident in regs

  f32x4 acc[2][8] = {};
#pragma unroll
  for (int kc = 0; kc < 8; ++kc) {
    const int kb = kc >> 1, kk = kc & 1;
    bf16x8 b[8];
#pragma unroll
    for (int j = 0; j < 8; ++j)
      b[j] = *(const bf16x8*)
          &Bsh[kb][(j * 16 + frow) * 64 + ((kk * 4 + quad) ^ f7) * 8];
#pragma unroll
    for (int j = 0; j < 8; ++j) {
      acc[0][j] = __builtin_amdgcn_mfma_f32_16x16x32_bf16(aF[0][kc], b[j],
                                                          acc[0][j], 0, 0, 0);
      acc[1][j] = __builtin_amdgcn_mfma_f32_16x16x32_bf16(aF[1][kc], b[j],
                                                          acc[1][j], 0, 0, 0);
    }
  }

  // ---- epilogue. C/D layout: col = lane&15, row = quad*4 + reg.
  // Rows are wave-exclusive (wave w owns 32 rows) -> direct row-sum store.
  const int colq = frow;
  float cs[8] = {};
#pragma unroll
  for (int m = 0; m < 2; ++m) {
#pragma unroll
    for (int r = 0; r < 4; ++r) {
      int row = bm + w * 32 + m * 16 + quad * 4 + r;
      float rs = 0.0f;
#pragma unroll
      for (int j = 0; j < 8; ++j) {
        int col = bn + j * 16 + colq;
        float v = acc[m][j][r];
        float e = __expf(v * TEMP_INV);
        e = (isDiag && col == row) ? 0.0f : e;
        rs += e;
        cs[j] += e;
        if (isPos && col == row + B) { pos[row] = v; pos[col] = v; }
      }
      rs += __shfl_xor(rs, 1);
      rs += __shfl_xor(rs, 2);
      rs += __shfl_xor(rs, 4);
      rs += __shfl_xor(rs, 8);
      if (colq == 0) part[(size_t)bx * N + row] = rs;
    }
  }
  // col sums need cross-wave combine (each wave spans all 128 cols)
  float* colbuf = (float*)&Bsh[0][0];  // [128][4]
  __syncthreads();  // all waves done reading Bsh
#pragma unroll
  for (int j = 0; j < 8; ++j) {
    float c = cs[j];
    c += __shfl_xor(c, 16);
    c += __shfl_xor(c, 32);
    if (quad == 0) colbuf[(j * 16 + colq) * 4 + w] = c;
  }
  __syncthreads();
  // part slot layout: for row idx in row-tile ty, slot s holds contribution
  // of block (ty,s) row-sum (s>=ty) or block (s,ty) col-sum (s<ty).
  if (!isDiag && tid < 128) {
    part[(size_t)by * N + bn + tid] = colbuf[tid * 4 + 0] + colbuf[tid * 4 + 1] +
                                      colbuf[tid * 4 + 2] + colbuf[tid * 4 + 3];
  }
}

// ---------------- kernel 3: reduce partials + finalize loss scalar -------
// 32 blocks x 256 threads; thread owns one global row idx.
__global__ void __launch_bounds__(256) finalize(
    const float* __restrict__ part, const float* __restrict__ pos,
    float* __restrict__ out, int N) {
  const int idx = blockIdx.x * 256 + threadIdx.x;
  const int NS = N / 128;  // 64 slots
  float s = 0.0f;
#pragma unroll 8
  for (int k = 0; k < NS; ++k) s += part[(size_t)k * N + idx];
  float loss = __logf(s) - pos[idx] * TEMP_INV;
  for (int off = 32; off; off >>= 1) loss += __shfl_xor(loss, off);
  __shared__ float redsh[4];
  if ((threadIdx.x & 63) == 0) redsh[threadIdx.x >> 6] = loss;
  __syncthreads();
  if (threadIdx.x == 0) {
    float t = redsh[0] + redsh[1] + redsh[2] + redsh[3];
    atomicAdd(out, t / (float)N);
  }
}

extern "C" void kernel_launch(void* const* d_in, const int* in_sizes, int n_in,
                              void* d_out, int out_size, void* d_ws, size_t ws_size,
                              hipStream_t stream) {
  const float* zi = (const float*)d_in[0];
  const float* zj = (const float*)d_in[1];
  const int B = in_sizes[0] / D;  // 4096
  const int N = 2 * B;            // 8192

  __hip_bfloat16* zn = (__hip_bfloat16*)d_ws;
  float* pos = (float*)((char*)d_ws + (size_t)N * D * sizeof(__hip_bfloat16));
  float* part = pos + N;          // [N/128][N] floats = 2 MB

  normalize_rows<<<512, 256, 0, stream>>>(zi, zj, zn, (float*)d_out, B);
  ntxent_gemm<<<NTILES, 256, 0, stream>>>(zn, part, pos, B);
  finalize<<<N / 256, 256, 0, stream>>>(part, pos, (float*)d_out, N);
}

// Round 6
// 99.215 us; speedup vs baseline: 1.1640x; 1.1351x over previous
//
#include <hip/hip_runtime.h>
#include <hip/hip_bf16.h>
#include <cstdint>
#include <cstddef>
#include <math.h>

#define D 256
#define TEMP_INV 2.0f       // 1 / TEMPERATURE, TEMPERATURE = 0.5
#define EPS_NORM 1e-8f
#define NTILES 2080         // 64*65/2 upper-triangular 128x128 tiles

typedef __attribute__((ext_vector_type(8))) short bf16x8;
typedef __attribute__((ext_vector_type(4))) float f32x4;

// ---------------- kernel 1: normalize rows, write bf16 zn ----------------
// 512 blocks x 4 waves, grid-stride over 8192 rows (4 rows/wave).
__global__ void __launch_bounds__(256) normalize_rows(
    const float* __restrict__ zi, const float* __restrict__ zj,
    __hip_bfloat16* __restrict__ zn, float* __restrict__ out, int B) {
  const int wid = threadIdx.x >> 6;
  const int lane = threadIdx.x & 63;
  if (blockIdx.x == 0 && threadIdx.x == 0) out[0] = 0.0f;  // for finalize atomic
#pragma unroll
  for (int it = 0; it < 4; ++it) {
    int row = it * 2048 + blockIdx.x * 4 + wid;
    const float* src = (row < B) ? (zi + (size_t)row * D)
                                 : (zj + (size_t)(row - B) * D);
    float4 v = ((const float4*)src)[lane];
    float ss = v.x * v.x + v.y * v.y + v.z * v.z + v.w * v.w;
    for (int off = 32; off; off >>= 1) ss += __shfl_xor(ss, off);
    float rn = 1.0f / fmaxf(sqrtf(ss), EPS_NORM);
    union { ushort4 u; __hip_bfloat16 h[4]; } o;
    o.h[0] = __float2bfloat16(v.x * rn);
    o.h[1] = __float2bfloat16(v.y * rn);
    o.h[2] = __float2bfloat16(v.z * rn);
    o.h[3] = __float2bfloat16(v.w * rn);
    ((ushort4*)zn)[(size_t)row * (D / 4) + lane] = o.u;
  }
}

// ---------------- kernel 2: fused sim GEMM + exp + masked row/col sums ---
// Upper-triangular 128x128 tiles, 2080 blocks, BK=64 K-loop (R9 structure).
//
// R13: REVERT to the best measured structure + ONE new lever.
// Evidence ledger: R9 (32KB LDS, (256,4) => 4 blocks/CU) gemm ~37us;
// R10/R11/R12 (64KB LDS => 2 blocks/CU; three totally different staging
// paths: dbuf gload_lds / no-K-loop gload_lds / reg-staged ds_write) all
// 51-54us with identical counters. Only occupancy has ever moved gemm.
// Static models predict 7-12us => per-block wall time is ~4x any static
// account: memory-LATENCY-bound (L2-miss -> L3 on panel first-touch),
// insufficient TLP at 2 blocks/CU to cover it.
// New lever: XCD-aware tile chunking. blockIdx -> XCD is round-robin (%8);
// t = (bid&7)*260 + (bid>>3) gives each XCD a CONTIGUOUS run of 260
// triangular-flattened tiles (2080 = 8*260, bijective). Consecutive tiles
// share A-panels => each XCD's private 4MB L2 keeps its panels hot,
// converting panel loads from ~600cy L3 visits to ~200cy L2 hits.
// Staging: lane-SEQUENTIAL float4 global loads -> regs -> ds_write_b128
// with XOR swizzle on the LDS ADDRESS (0 conflicts, verified R4-R9).
__device__ __forceinline__ void decode_tile(int t, int Nb, int& by, int& bx) {
  float fb = (2.0f * Nb + 1.0f -
              sqrtf((float)((2 * Nb + 1) * (2 * Nb + 1) - 8 * t))) * 0.5f;
  int y = (int)fb;
  while ((y + 1) * Nb - ((y + 1) * y) / 2 <= t) ++y;
  while (y * Nb - (y * (y - 1)) / 2 > t) --y;
  by = y;
  bx = y + (t - (y * Nb - (y * (y - 1)) / 2));
}

__global__ void __launch_bounds__(256, 4) ntxent_gemm(
    const __hip_bfloat16* __restrict__ zn,
    float* __restrict__ part, float* __restrict__ pos, int B) {
  __shared__ __align__(16) __hip_bfloat16 Ash[128 * 64];  // 16 KB
  __shared__ __align__(16) __hip_bfloat16 Bsh[128 * 64];  // 16 KB

  const int N = 2 * B;
  const int Nb = N / 128;  // 64
  // XCD-aware chunking: XCD (bid%8) gets contiguous tile run [x*260,(x+1)*260)
  const int t = (blockIdx.x & 7) * (NTILES / 8) + (blockIdx.x >> 3);
  int by, bx;
  decode_tile(t, Nb, by, bx);
  const int bm = by * 128;
  const int bn = bx * 128;
  const bool isDiag = (by == bx);
  const bool isPos = (bx == by + B / 128);

  const int tid = threadIdx.x;
  const int wid = tid >> 6;
  const int lane = tid & 63;
  const int wy = wid >> 1, wx = wid & 1;
  const int wrow0 = wid * 32;

  const int lr = lane >> 3;     // row within 8-row staging group (== r&7)
  const int c8 = lane & 7;      // 16B chunk, SEQUENTIAL in global memory

  const int frow = lane & 15;
  const int quad = lane >> 4;
  const int f7 = frow & 7;

  f32x4 acc[4][4] = {};

  // staging addresses: row r(s) = wrow0 + s*8 + lr; global byte col = c8*16
  const __hip_bfloat16* gA = zn + (size_t)(bm + wrow0 + lr) * D + c8 * 8;
  const __hip_bfloat16* gB = zn + (size_t)(bn + wrow0 + lr) * D + c8 * 8;
  // LDS write: row r, chunk c8 ^ (r&7); r&7 == lr for every s (s*8 step)
  const int ldsoff = (wrow0 + lr) * 64 + (c8 ^ lr) * 8;

  // prologue: stage slab k0=0 into registers
  float4 va0 = *(const float4*)(gA + 0 * 8 * D);
  float4 va1 = *(const float4*)(gA + 1 * 8 * D);
  float4 va2 = *(const float4*)(gA + 2 * 8 * D);
  float4 va3 = *(const float4*)(gA + 3 * 8 * D);
  float4 vb0 = *(const float4*)(gB + 0 * 8 * D);
  float4 vb1 = *(const float4*)(gB + 1 * 8 * D);
  float4 vb2 = *(const float4*)(gB + 2 * 8 * D);
  float4 vb3 = *(const float4*)(gB + 3 * 8 * D);

#pragma unroll
  for (int k0i = 0; k0i < 4; ++k0i) {
    __syncthreads();  // WAR: previous slab's LDS reads complete
    *(float4*)&Ash[ldsoff + 0 * 8 * 64] = va0;
    *(float4*)&Ash[ldsoff + 1 * 8 * 64] = va1;
    *(float4*)&Ash[ldsoff + 2 * 8 * 64] = va2;
    *(float4*)&Ash[ldsoff + 3 * 8 * 64] = va3;
    *(float4*)&Bsh[ldsoff + 0 * 8 * 64] = vb0;
    *(float4*)&Bsh[ldsoff + 1 * 8 * 64] = vb1;
    *(float4*)&Bsh[ldsoff + 2 * 8 * 64] = vb2;
    *(float4*)&Bsh[ldsoff + 3 * 8 * 64] = vb3;
    __syncthreads();
    // prefetch next slab: latency hides under the ds_read+MFMA phase below
    if (k0i < 3) {
      const int k0 = (k0i + 1) * 64;
      va0 = *(const float4*)(gA + 0 * 8 * D + k0);
      va1 = *(const float4*)(gA + 1 * 8 * D + k0);
      va2 = *(const float4*)(gA + 2 * 8 * D + k0);
      va3 = *(const float4*)(gA + 3 * 8 * D + k0);
      vb0 = *(const float4*)(gB + 0 * 8 * D + k0);
      vb1 = *(const float4*)(gB + 1 * 8 * D + k0);
      vb2 = *(const float4*)(gB + 2 * 8 * D + k0);
      vb3 = *(const float4*)(gB + 3 * 8 * D + k0);
    }
#pragma unroll
    for (int kk = 0; kk < 2; ++kk) {
      bf16x8 a[4], b[4];
#pragma unroll
      for (int i = 0; i < 4; ++i)
        a[i] = *(const bf16x8*)
            &Ash[(wy * 64 + i * 16 + frow) * 64 + ((kk * 4 + quad) ^ f7) * 8];
#pragma unroll
      for (int j = 0; j < 4; ++j)
        b[j] = *(const bf16x8*)
            &Bsh[(wx * 64 + j * 16 + frow) * 64 + ((kk * 4 + quad) ^ f7) * 8];
#pragma unroll
      for (int i = 0; i < 4; ++i)
#pragma unroll
        for (int j = 0; j < 4; ++j)
          acc[i][j] =
              __builtin_amdgcn_mfma_f32_16x16x32_bf16(a[i], b[j], acc[i][j], 0, 0, 0);
    }
  }

  // ---- epilogue: exp + masked row/col sums -> LDS combine -> part writes
  float* red = (float*)&Ash[0];  // red[0..255]: rowbuf[128][2] (x wx)
                                 // red[256..511]: colbuf[128][2] (x wy)

  // C/D layout: col = lane&15, row = quad*4 + reg
  const int colq = lane & 15;
  float cs[4] = {0.0f, 0.0f, 0.0f, 0.0f};
#pragma unroll
  for (int i = 0; i < 4; ++i) {
#pragma unroll
    for (int r = 0; r < 4; ++r) {
      int rowloc = wy * 64 + i * 16 + quad * 4 + r;
      int row = bm + rowloc;
      float rs = 0.0f;
#pragma unroll
      for (int j = 0; j < 4; ++j) {
        int col = bn + wx * 64 + j * 16 + colq;
        float v = acc[i][j][r];
        float e = __expf(v * TEMP_INV);
        e = (isDiag && col == row) ? 0.0f : e;
        rs += e;
        cs[j] += e;
        if (isPos && col == row + B) { pos[row] = v; pos[col] = v; }
      }
      rs += __shfl_xor(rs, 1);
      rs += __shfl_xor(rs, 2);
      rs += __shfl_xor(rs, 4);
      rs += __shfl_xor(rs, 8);
      if (colq == 0) red[rowloc * 2 + wx] = rs;
    }
  }
#pragma unroll
  for (int j = 0; j < 4; ++j) {
    float c = cs[j];
    c += __shfl_xor(c, 16);
    c += __shfl_xor(c, 32);
    if (quad == 0) red[256 + (wx * 64 + j * 16 + colq) * 2 + wy] = c;
  }
  __syncthreads();
  // part slot layout: for global row idx in row-tile ty, slot s holds the
  // contribution of column-tile s (row-sum from block (ty,s), s>=ty) or
  // row-tile s (col-sum from block (s,ty), s<ty). Each slot written once.
  if (tid < 128) {
    part[(size_t)bx * N + bm + tid] = red[tid * 2] + red[tid * 2 + 1];
  } else if (!isDiag) {
    int tt = tid - 128;
    part[(size_t)by * N + bn + tt] = red[256 + tt * 2] + red[256 + tt * 2 + 1];
  }
}

// ---------------- kernel 3: reduce partials + finalize loss scalar -------
// 32 blocks x 256 threads; thread owns one global row idx.
__global__ void __launch_bounds__(256) finalize(
    const float* __restrict__ part, const float* __restrict__ pos,
    float* __restrict__ out, int N) {
  const int idx = blockIdx.x * 256 + threadIdx.x;
  const int NS = N / 128;  // 64 slots
  float s = 0.0f;
#pragma unroll 8
  for (int k = 0; k < NS; ++k) s += part[(size_t)k * N + idx];
  float loss = __logf(s) - pos[idx] * TEMP_INV;
  for (int off = 32; off; off >>= 1) loss += __shfl_xor(loss, off);
  __shared__ float redsh[4];
  if ((threadIdx.x & 63) == 0) redsh[threadIdx.x >> 6] = loss;
  __syncthreads();
  if (threadIdx.x == 0) {
    float tt = redsh[0] + redsh[1] + redsh[2] + redsh[3];
    atomicAdd(out, tt / (float)N);
  }
}

extern "C" void kernel_launch(void* const* d_in, const int* in_sizes, int n_in,
                              void* d_out, int out_size, void* d_ws, size_t ws_size,
                              hipStream_t stream) {
  const float* zi = (const float*)d_in[0];
  const float* zj = (const float*)d_in[1];
  const int B = in_sizes[0] / D;  // 4096
  const int N = 2 * B;            // 8192

  __hip_bfloat16* zn = (__hip_bfloat16*)d_ws;
  float* pos = (float*)((char*)d_ws + (size_t)N * D * sizeof(__hip_bfloat16));
  float* part = pos + N;          // [N/128][N] floats = 2 MB

  normalize_rows<<<512, 256, 0, stream>>>(zi, zj, zn, (float*)d_out, B);
  ntxent_gemm<<<NTILES, 256, 0, stream>>>(zn, part, pos, B);
  finalize<<<N / 256, 256, 0, stream>>>(part, pos, (float*)d_out, N);
}